// Round 12
// baseline (135.562 us; speedup 1.0000x reference)
//
#include <hip/hip_runtime.h>

// VQ quantizer: N=131072 rows, K=1024 codes, D=10, fp32.
// R9 (4th submit; three consecutive broker timeouts, never measured).
// Barrier-flat. Same math as R6/R7 (absmax 0.0): score = x.e - 0.5||e||^2
// via mfma_f32_32x32x16_bf16, exact fp32->3xbf16 splits, 6 product terms
// (hh,hm,hl,mh,mm,lh) in R6's verified order; ms=-0.5||e||^2 triple-split in
// k-slots 10..12 of A-v0 against bf16(1.0) in B-v0.
// Restructure vs R7: (1) A-fragments built IN-KERNEL from E (no prep kernel,
// no g_afrag round trip); (2) ALL 8 row-groups' B-tables built up front
// (256 thr, 24 KB LDS); (3) group loop is barrier-free (per-wave LDS result
// slots); (4) ONE sync, then fully parallel 256-thread merge+epilogue.
// Barriers per block: 16 -> 2.  512 blocks x 512 thr, launch_bounds(512,4).

typedef __attribute__((ext_vector_type(8))) short short8;
typedef __attribute__((ext_vector_type(16))) float f32x16;

constexpr int N = 131072;
constexpr int K = 1024;
constexpr int D = 10;
constexpr int THREADS = 512;           // 8 waves
constexpr int BLOCKS = 512;
constexpr int RPB = 256;               // rows per block
constexpr int GROUPS = 8;              // row-groups of 32
constexpr int RPG = 32;
constexpr int TPW = 4;                 // code-tiles per wave (8 waves x 4 = 32)

__device__ inline unsigned short f2bf(float f) {        // RNE fp32->bf16
    unsigned u = __float_as_uint(f);
    u += 0x7FFFu + ((u >> 16) & 1u);
    return (unsigned short)(u >> 16);
}
__device__ inline float bf2f(unsigned short h) {
    return __uint_as_float(((unsigned)h) << 16);
}

// Build one x-row's B fragments: sB[(g*6 + v*2 + h)*32 + row].
// Slot content identical to R6/R7 (absmax 0.0 verified).
__device__ inline void build_b_row(const float* __restrict__ x, int grow,
                                   int g, int row, short8* __restrict__ sB) {
    const float* xp = x + (size_t)grow * D;
    float xv[D];
    #pragma unroll
    for (int d = 0; d < D; d += 2) {
        float2 t2 = *reinterpret_cast<const float2*>(xp + d);
        xv[d] = t2.x; xv[d + 1] = t2.y;
    }
    unsigned short XH[D], XM[D], XL[D];
    #pragma unroll
    for (int d = 0; d < D; ++d) {
        XH[d] = f2bf(xv[d]); const float r1 = xv[d] - bf2f(XH[d]);
        XM[d] = f2bf(r1);    XL[d] = f2bf(r1 - bf2f(XM[d]));
    }
    unsigned short slots[48];
    #pragma unroll
    for (int s = 0; s < 16; ++s) {
        slots[s]      = (s < D) ? XH[s]
                      : (s <= 12 ? (unsigned short)0x3F80 : (unsigned short)0); // bf16 1.0
        slots[16 + s] = (s < D) ? XM[s] : (unsigned short)0;
        slots[32 + s] = (s < D) ? XL[s] : (unsigned short)0;
    }
    #pragma unroll
    for (int v = 0; v < 3; ++v)
        #pragma unroll
        for (int h = 0; h < 2; ++h) {
            short8 w;
            #pragma unroll
            for (int i = 0; i < 8; ++i) w[i] = (short)slots[v * 16 + h * 8 + i];
            sB[(g * 6 + v * 2 + h) * 32 + row] = w;
        }
}

#define MFMA __builtin_amdgcn_mfma_f32_32x32x16_bf16

__global__ __launch_bounds__(THREADS, 4) void vq_kernel(
    const float* __restrict__ x,
    const float* __restrict__ E,
    float* __restrict__ out,
    float* __restrict__ loss_out)
{
    __shared__ short8 sB[GROUPS * 6 * 32];          // 24 KB
    __shared__ float  sScore[8][RPB];               // 8 KB
    __shared__ unsigned short sIdxs[8][RPB];        // 4 KB   (total 36 KB)

    const int tid  = threadIdx.x;
    const int lane = tid & 63;
    const int wave = tid >> 6;
    const int n    = lane & 31;
    const int hf   = lane >> 5;
    const int hibase = hf * 4;
    const int wtile  = wave * TPW;
    const int blockRow = blockIdx.x * RPB;

    // ---- A fragments built in-registers straight from E ----
    // Lane L covers code (wtile+t)*32 + (L&31), k-slots hf*8+i.
    // Split math identical to R6/R7 prep_afrag.
    short8 a[TPW][3];
    #pragma unroll
    for (int t = 0; t < TPW; ++t) {
        const int code = (wtile + t) * 32 + n;
        const float* ep = E + (size_t)code * D;
        float e[D];
        #pragma unroll
        for (int d = 0; d < D; d += 2) {
            float2 t2 = *reinterpret_cast<const float2*>(ep + d);
            e[d] = t2.x; e[d + 1] = t2.y;
        }
        float s = 0.f;
        #pragma unroll
        for (int d = 0; d < D; ++d) s = fmaf(e[d], e[d], s);   // same chain R1-R8
        const float ms = -0.5f * s;
        const unsigned short msh = f2bf(ms);
        const float r1 = ms - bf2f(msh);
        const unsigned short msm = f2bf(r1);
        const unsigned short msl = f2bf(r1 - bf2f(msm));

        #pragma unroll
        for (int v = 0; v < 3; ++v) {
            short8 w;
            #pragma unroll
            for (int i = 0; i < 8; ++i) {
                const int k = hf * 8 + i;
                unsigned short o = 0;
                if (k < D) {
                    const unsigned short eh = f2bf(e[k]);
                    if (v == 0) o = eh;
                    else {
                        const float rm = e[k] - bf2f(eh);
                        const unsigned short em = f2bf(rm);
                        o = (v == 1) ? em : f2bf(rm - bf2f(em));
                    }
                } else if (v == 0) {
                    o = (k == 10) ? msh : (k == 11) ? msm
                      : (k == 12) ? msl : (unsigned short)0;
                }
                w[i] = (short)o;
            }
            a[t][v] = w;
        }
    }

    // ---- ALL groups' B tables up front: thread t<256 builds row t ----
    if (tid < RPB) build_b_row(x, blockRow + tid, tid >> 5, tid & 31, sB);
    __syncthreads();

    // ---- barrier-free sweep: 8 groups x (3 LDS reads + 12 MFMA + argmax) ----
    for (int g = 0; g < GROUPS; ++g) {
        const short8 b0 = sB[(g * 6 + 0 + hf) * 32 + n];
        const short8 b1 = sB[(g * 6 + 2 + hf) * 32 + n];
        const short8 b2 = sB[(g * 6 + 4 + hf) * 32 + n];

        float best = -3.0e38f;
        int   lci  = 0;                     // local code id: t*16 + r

        #pragma unroll
        for (int p = 0; p < TPW / 2; ++p) { // tile pairs: dep-distance-2 chains
            const int t0 = 2 * p, t1 = 2 * p + 1;
            f32x16 c0, c1;
            #pragma unroll
            for (int i = 0; i < 16; ++i) { c0[i] = 0.f; c1[i] = 0.f; }
            c0 = MFMA(a[t0][0], b0, c0, 0, 0, 0);  c1 = MFMA(a[t1][0], b0, c1, 0, 0, 0);
            c0 = MFMA(a[t0][0], b1, c0, 0, 0, 0);  c1 = MFMA(a[t1][0], b1, c1, 0, 0, 0);
            c0 = MFMA(a[t0][0], b2, c0, 0, 0, 0);  c1 = MFMA(a[t1][0], b2, c1, 0, 0, 0);
            c0 = MFMA(a[t0][1], b0, c0, 0, 0, 0);  c1 = MFMA(a[t1][1], b0, c1, 0, 0, 0);
            c0 = MFMA(a[t0][1], b1, c0, 0, 0, 0);  c1 = MFMA(a[t1][1], b1, c1, 0, 0, 0);
            c0 = MFMA(a[t0][2], b0, c0, 0, 0, 0);  c1 = MFMA(a[t1][2], b0, c1, 0, 0, 0);

            #pragma unroll
            for (int r = 0; r < 16; ++r) {         // ascending codes within half
                const bool gt = c0[r] > best;      // strict >: first idx wins
                lci  = gt ? (t0 * 16 + r) : lci;
                best = fmaxf(best, c0[r]);
            }
            #pragma unroll
            for (int r = 0; r < 16; ++r) {
                const bool gt = c1[r] > best;
                lci  = gt ? (t1 * 16 + r) : lci;
                best = fmaxf(best, c1[r]);
            }
        }

        const int tt = lci >> 4, rr = lci & 15;
        int bidx = (wtile + tt) * 32 + hibase + ((rr & 3) + 8 * (rr >> 2));

        // merge lane halves (codes interleave 4-apart: explicit idx tie-break)
        {
            const float pb = __shfl_xor(best, 32, 64);
            const int   pi = __shfl_xor(bidx, 32, 64);
            const bool take = (pb > best) || (pb == best && pi < bidx);
            best = take ? pb : best;  bidx = take ? pi : bidx;
        }
        if (lane < 32) {
            sScore[wave][g * RPG + n] = best;
            sIdxs[wave][g * RPG + n]  = (unsigned short)bidx;
        }
    }
    __syncthreads();

    // ---- fully parallel merge + epilogue: thread t<256 owns row t ----
    float lsum = 0.f;
    if (tid < RPB) {
        float bs = sScore[0][tid];
        int   bi = sIdxs[0][tid];
        #pragma unroll
        for (int w = 1; w < 8; ++w) {          // ascending wave = ascending codes
            const float s  = sScore[w][tid];
            const int   i2 = sIdxs[w][tid];
            if (s > bs) { bs = s; bi = i2; }   // strict >: first index wins
        }
        const float* ep = E   + (size_t)bi * D;            // L2-hot gather
        const float* xp = x   + (size_t)(blockRow + tid) * D;
        float*       op = out + (size_t)(blockRow + tid) * D;
        #pragma unroll
        for (int d = 0; d < D; d += 2) {
            float2 ev = *reinterpret_cast<const float2*>(ep + d);
            float2 xw = *reinterpret_cast<const float2*>(xp + d);
            const float d0 = xw.x - ev.x, d1 = xw.y - ev.y;
            lsum = fmaf(d0, d0, lsum);  lsum = fmaf(d1, d1, lsum);
            float2 o;
            o.x = xw.x + (ev.x - xw.x);        // literal STE expression
            o.y = xw.y + (ev.y - xw.y);
            *reinterpret_cast<float2*>(op + d) = o;
        }
    }

    // ---- loss: shuffle reduce (waves 4-7 contribute zeros) + 1 atomic/wave ----
    #pragma unroll
    for (int off = 32; off > 0; off >>= 1)
        lsum += __shfl_down(lsum, off, 64);
    if (lane == 0)
        atomicAdd(loss_out, lsum * (1.0f / ((float)N * (float)D)));
}

extern "C" void kernel_launch(void* const* d_in, const int* in_sizes, int n_in,
                              void* d_out, int out_size, void* d_ws, size_t ws_size,
                              hipStream_t stream) {
    const float* x = (const float*)d_in[0];   // encoder_embedding [N, D]
    const float* E = (const float*)d_in[1];   // embedding_weight  [K, D]
    float* out  = (float*)d_out;              // quantized_st [N*D] then loss [1]
    float* loss = out + (size_t)N * D;

    hipMemsetAsync(loss, 0, sizeof(float), stream);       // d_out re-poisoned
    vq_kernel<<<dim3(BLOCKS), dim3(THREADS), 0, stream>>>(x, E, out, loss);
}